// Round 1
// baseline (280.637 us; speedup 1.0000x reference)
//
#include <hip/hip_runtime.h>

#define BATCH 4
#define SQL 2048
#define SKL 2048
#define DIM 512
#define NR 257
#define NRP 288
#define RAD 128

typedef __bf16 bf16x8 __attribute__((ext_vector_type(8)));
typedef float f32x4 __attribute__((ext_vector_type(4)));
typedef unsigned short u16;
typedef u16 u16x4 __attribute__((ext_vector_type(4)));
typedef u16 u16x8 __attribute__((ext_vector_type(8)));

__device__ inline u16 f2bf(float x) {
  union { float f; unsigned u; } v; v.f = x;
  unsigned r = v.u + 0x7FFF + ((v.u >> 16) & 1);   // RNE
  return (u16)(r >> 16);
}

// 8 fp32 -> bf16x8, with a multiplicative mask (0 or 1) for guarded rows
__device__ inline bf16x8 cvt8m(f32x4 lo, f32x4 hi, float m) {
  u16x8 o;
#pragma unroll
  for (int e = 0; e < 4; e++) o[e] = f2bf(lo[e] * m);
#pragma unroll
  for (int e = 0; e < 4; e++) o[e + 4] = f2bf(hi[e] * m);
  union { u16x8 u; bf16x8 b; } c; c.u = o; return c.b;
}

__device__ inline void glds16(const u16* g, const u16* l) {
  __builtin_amdgcn_global_load_lds(
      (const __attribute__((address_space(1))) void*)g,
      (__attribute__((address_space(3))) void*)l, 16, 0, 0);
}

// ---------------- fused prep kernel ----------------
// blocks [0,4096):    cvt Q fp32 -> bf16
// blocks [4096,8192): cvt K fp32 -> bf16
// blocks [8192,12288): transpose V [b][k][d] fp32 -> Vt [b][d][k] bf16
// blocks [12288,13440): Qrel = Q @ rel^T (fp32 inputs, bf16 MFMA) -> fp32 [8192][NRP]
__global__ __launch_bounds__(256) void prep_kernel(const float* __restrict__ Q,
                                                   const float* __restrict__ K,
                                                   const float* __restrict__ V,
                                                   const float* __restrict__ rel,
                                                   u16x4* __restrict__ Qb,
                                                   u16x4* __restrict__ Kb,
                                                   u16* __restrict__ Vt,
                                                   float* __restrict__ Qrel) {
  __shared__ float tile[32][33];
  int bid = blockIdx.x, tid = threadIdx.x;
  if (bid < 8192) {
    const f32x4* src = (bid < 4096) ? (const f32x4*)Q : (const f32x4*)K;
    u16x4* dst = (bid < 4096) ? Qb : Kb;
    int i = (bid & 4095) * 256 + tid;     // exactly covers 1048576 f32x4
    f32x4 f = src[i];
    u16x4 o;
#pragma unroll
    for (int e = 0; e < 4; e++) o[e] = f2bf(f[e]);
    dst[i] = o;
  } else if (bid < 12288) {
    int t = bid - 8192;
    int b = t >> 10, rem = t & 1023;
    int k0 = (rem & 63) * 32, d0 = (rem >> 6) * 32;
    int tx = tid & 31, ty = tid >> 5;     // 32 x 8
#pragma unroll
    for (int r = 0; r < 4; r++)
      tile[ty + r * 8][tx] = V[((long)b * SKL + k0 + ty + r * 8) * DIM + d0 + tx];
    __syncthreads();
#pragma unroll
    for (int r = 0; r < 4; r++)
      Vt[((long)b * DIM + d0 + ty + r * 8) * SKL + k0 + tx] = f2bf(tile[tx][ty + r * 8]);
  } else {
    int t = bid - 12288;
    int xb = t & 127, yb = t >> 7;        // 128 x 9
    int wave = tid >> 6, lane = tid & 63;
    int m0 = xb * 64 + wave * 16;
    int j0 = yb * 2;                      // col tiles j0, j0+1
    int fr = lane & 15, fk = (lane >> 4) * 8;
    f32x4 acc[2] = {};
    const float* qrow = Q + (long)(m0 + fr) * DIM + fk;
    int r0r = j0 * 16 + fr, r1r = r0r + 16;
    // clamp row so loads stay in-bounds; mask result to zero for pad rows
    int r0c = r0r < NR ? r0r : NR - 1;
    int r1c = r1r < NR ? r1r : NR - 1;
    float g0 = r0r < NR ? 1.0f : 0.0f;
    float g1 = r1r < NR ? 1.0f : 0.0f;
    const float* r0p = rel + (long)r0c * DIM + fk;
    const float* r1p = rel + (long)r1c * DIM + fk;
    for (int k0 = 0; k0 < DIM; k0 += 32) {
      bf16x8 a = cvt8m(*(const f32x4*)(qrow + k0), *(const f32x4*)(qrow + k0 + 4), 1.0f);
      bf16x8 b0 = cvt8m(*(const f32x4*)(r0p + k0), *(const f32x4*)(r0p + k0 + 4), g0);
      bf16x8 b1 = cvt8m(*(const f32x4*)(r1p + k0), *(const f32x4*)(r1p + k0 + 4), g1);
      acc[0] = __builtin_amdgcn_mfma_f32_16x16x32_bf16(a, b0, acc[0], 0, 0, 0);
      acc[1] = __builtin_amdgcn_mfma_f32_16x16x32_bf16(a, b1, acc[1], 0, 0, 0);
    }
    int cr = (lane >> 4) * 4, cc = lane & 15;
#pragma unroll
    for (int t2 = 0; t2 < 2; t2++)
#pragma unroll
      for (int r = 0; r < 4; r++)
        Qrel[(long)(m0 + cr + r) * NRP + (j0 + t2) * 16 + cc] = acc[t2][r];
  }
}

// ---------------- energy: S = bf16(Q K^T / sqrt(d)) (rel added in softmax) ----------------
// 128x128 tile, 4 waves (2x2 of 64x64), BK=32, global_load_lds staging
__global__ __launch_bounds__(256) void energy_kernel(const u16* __restrict__ Qb,
                                                     const u16* __restrict__ Kb,
                                                     u16* __restrict__ S) {
  int b = blockIdx.z;
  int m0 = blockIdx.y * 128;
  int n0 = blockIdx.x * 128;
  const u16* A = Qb + (long)b * SQL * DIM;
  const u16* Bp = Kb + (long)b * SKL * DIM;
  __shared__ u16 As[128 * 32];
  __shared__ u16 Bs[128 * 32];
  int tid = threadIdx.x;
  int wave = tid >> 6, lane = tid & 63;
  int wm = (wave >> 1) * 64, wn = (wave & 1) * 64;
  int fr = lane & 15, fk = (lane >> 4) * 8;
  int srow = wave * 32 + (lane >> 2);
  int scol = (lane & 3) * 8;
  f32x4 acc[4][4] = {};
  for (int k0 = 0; k0 < DIM; k0 += 32) {
    __syncthreads();
    glds16(A + (long)(m0 + srow) * DIM + k0 + scol, As + (wave * 2 + 0) * 512);
    glds16(A + (long)(m0 + srow + 16) * DIM + k0 + scol, As + (wave * 2 + 1) * 512);
    glds16(Bp + (long)(n0 + srow) * DIM + k0 + scol, Bs + (wave * 2 + 0) * 512);
    glds16(Bp + (long)(n0 + srow + 16) * DIM + k0 + scol, Bs + (wave * 2 + 1) * 512);
    __syncthreads();
    bf16x8 af[4], bfr[4];
#pragma unroll
    for (int i = 0; i < 4; i++) af[i] = *(const bf16x8*)(As + (wm + i * 16 + fr) * 32 + fk);
#pragma unroll
    for (int j = 0; j < 4; j++) bfr[j] = *(const bf16x8*)(Bs + (wn + j * 16 + fr) * 32 + fk);
#pragma unroll
    for (int i = 0; i < 4; i++)
#pragma unroll
      for (int j = 0; j < 4; j++)
        acc[i][j] = __builtin_amdgcn_mfma_f32_16x16x32_bf16(af[i], bfr[j], acc[i][j], 0, 0, 0);
  }
  const float inv_norm = 0.04419417382415922f;  // 1/sqrt(512)
  int cr = (lane >> 4) * 4, cc = lane & 15;
#pragma unroll
  for (int i = 0; i < 4; i++) {
#pragma unroll
    for (int r = 0; r < 4; r++) {
      int q = m0 + wm + i * 16 + cr + r;
      u16* sr = S + ((long)b * SQL + q) * SKL;
#pragma unroll
      for (int j = 0; j < 4; j++)
        sr[n0 + wn + j * 16 + cc] = f2bf(acc[i][j][r] * inv_norm);
    }
  }
}

// ---------------- softmax: logits + rel gather -> fp32 attn + bf16 probs (S in-place) ----
__global__ __launch_bounds__(256) void softmax_kernel(u16* __restrict__ S,
                                                      const float* __restrict__ Qrel,
                                                      float* __restrict__ attn) {
  long row = blockIdx.x;
  int q = (int)(row & (SQL - 1));
  u16* srow = S + row * SKL;
  float* arow = attn + row * SKL;
  int tid = threadIdx.x;
  int wave = tid >> 6, lane = tid & 63;
  __shared__ float qlds[NR];
  __shared__ float red[4];
  const float inv_norm = 0.04419417382415922f;
  const float* qr = Qrel + row * NRP;
  qlds[tid] = qr[tid] * inv_norm;          // tid 0..255
  if (tid == 0) qlds[256] = qr[256] * inv_norm;
  bf16x8 v = *(const bf16x8*)(srow + tid * 8);
  __syncthreads();
  float f[8];
  int kb = tid * 8 - q + RAD;
#pragma unroll
  for (int e = 0; e < 8; e++) {
    int idx = kb + e;
    idx = idx < 0 ? 0 : (idx > 2 * RAD ? 2 * RAD : idx);
    f[e] = (float)v[e] + qlds[idx];
  }
  float m = -1e30f;
#pragma unroll
  for (int e = 0; e < 8; e++) m = fmaxf(m, f[e]);
  for (int o = 32; o > 0; o >>= 1) m = fmaxf(m, __shfl_xor(m, o));
  if (lane == 0) red[wave] = m;
  __syncthreads();
  m = fmaxf(fmaxf(red[0], red[1]), fmaxf(red[2], red[3]));
  __syncthreads();
  float s = 0.0f;
  float e8[8];
#pragma unroll
  for (int e = 0; e < 8; e++) { e8[e] = __expf(f[e] - m); s += e8[e]; }
  for (int o = 32; o > 0; o >>= 1) s += __shfl_xor(s, o);
  if (lane == 0) red[wave] = s;
  __syncthreads();
  s = red[0] + red[1] + red[2] + red[3];
  float inv = 1.0f / s;
  f32x4 o0, o1;
  u16x8 pb;
#pragma unroll
  for (int e = 0; e < 4; e++) {
    float p = e8[e] * inv;
    o0[e] = p; pb[e] = f2bf(p);
  }
#pragma unroll
  for (int e = 0; e < 4; e++) {
    float p = e8[e + 4] * inv;
    o1[e] = p; pb[e + 4] = f2bf(p);
  }
  *(f32x4*)(arow + tid * 8) = o0;
  *(f32x4*)(arow + tid * 8 + 4) = o1;
  *(u16x8*)(srow + tid * 8) = pb;
}

// ---------------- Z = P @ V  (P = bf16 probs in S; Vt is [b][d][k] bf16) ----------------
// 64x128 tile (M x N), 4 waves (2x2 of 32x64), BK=32, global_load_lds staging
__global__ __launch_bounds__(256) void z_kernel(const u16* __restrict__ S,
                                                const u16* __restrict__ Vt,
                                                float* __restrict__ Z) {
  int b = blockIdx.z;
  int m0 = blockIdx.y * 64;
  int n0 = blockIdx.x * 128;
  const u16* A = S + (long)b * SQL * SKL;
  const u16* Bp = Vt + (long)b * DIM * SKL;
  __shared__ u16 As[64 * 32];
  __shared__ u16 Bs[128 * 32];
  int tid = threadIdx.x;
  int wave = tid >> 6, lane = tid & 63;
  int wm = (wave >> 1) * 32, wn = (wave & 1) * 64;
  int fr = lane & 15, fk = (lane >> 4) * 8;
  int srowA = wave * 16 + (lane >> 2);
  int srowB = wave * 32 + (lane >> 2);
  int scol = (lane & 3) * 8;
  f32x4 acc[2][4] = {};
  for (int k0 = 0; k0 < SKL; k0 += 32) {
    __syncthreads();
    glds16(A + (long)(m0 + srowA) * SKL + k0 + scol, As + wave * 512);
    glds16(Bp + (long)(n0 + srowB) * SKL + k0 + scol, Bs + (wave * 2 + 0) * 512);
    glds16(Bp + (long)(n0 + srowB + 16) * SKL + k0 + scol, Bs + (wave * 2 + 1) * 512);
    __syncthreads();
    bf16x8 af[2], bfr[4];
#pragma unroll
    for (int i = 0; i < 2; i++) af[i] = *(const bf16x8*)(As + (wm + i * 16 + fr) * 32 + fk);
#pragma unroll
    for (int j = 0; j < 4; j++) bfr[j] = *(const bf16x8*)(Bs + (wn + j * 16 + fr) * 32 + fk);
#pragma unroll
    for (int i = 0; i < 2; i++)
#pragma unroll
      for (int j = 0; j < 4; j++)
        acc[i][j] = __builtin_amdgcn_mfma_f32_16x16x32_bf16(af[i], bfr[j], acc[i][j], 0, 0, 0);
  }
  int cr = (lane >> 4) * 4, cc = lane & 15;
#pragma unroll
  for (int i = 0; i < 2; i++)
#pragma unroll
    for (int r = 0; r < 4; r++) {
      int q = m0 + wm + i * 16 + cr + r;
      float* zrow = Z + ((long)b * SQL + q) * DIM;
#pragma unroll
      for (int j = 0; j < 4; j++)
        zrow[n0 + wn + j * 16 + cc] = acc[i][j][r];
    }
}

// ---------------- launch ----------------

extern "C" void kernel_launch(void* const* d_in, const int* in_sizes, int n_in,
                              void* d_out, int out_size, void* d_ws, size_t ws_size,
                              hipStream_t stream) {
  const float* Q = (const float*)d_in[0];
  const float* K = (const float*)d_in[1];
  const float* V = (const float*)d_in[2];
  const float* rel = (const float*)d_in[3];
  float* attn = (float*)d_out;                       // [4][2048][2048]
  float* Z = attn + (long)BATCH * SQL * SKL;         // [4][2048][512]

  char* ws = (char*)d_ws;
  u16* Qb   = (u16*)ws;                    //  8 MiB  bf16 Q [b][q][d]
  u16* Kb   = (u16*)(ws + 8388608);        //  8 MiB  bf16 K [b][k][d]
  u16* Vt   = (u16*)(ws + 16777216);       //  8 MiB  bf16 V^T [b][d][k]
  float* Qrel = (float*)(ws + 25165824);   //  9 MiB  fp32 Qrel [8192][288]
  u16* S    = (u16*)(ws + 34603008);       //  32 MiB bf16 scores/probs [b][q][k]

  prep_kernel<<<13440, 256, 0, stream>>>(Q, K, V, rel, (u16x4*)Qb, (u16x4*)Kb, Vt, Qrel);
  energy_kernel<<<dim3(16, 16, BATCH), 256, 0, stream>>>(Qb, Kb, S);
  softmax_kernel<<<8192, 256, 0, stream>>>(S, Qrel, attn);
  z_kernel<<<dim3(4, 32, BATCH), 256, 0, stream>>>(S, Vt, Z);
}

// Round 2
// 239.794 us; speedup vs baseline: 1.1703x; 1.1703x over previous
//
#include <hip/hip_runtime.h>

#define BATCH 4
#define SQL 2048
#define SKL 2048
#define DIM 512
#define NR 257
#define NRP 288
#define RAD 128

typedef __bf16 bf16x8 __attribute__((ext_vector_type(8)));
typedef float f32x4 __attribute__((ext_vector_type(4)));
typedef unsigned short u16;
typedef u16 u16x4 __attribute__((ext_vector_type(4)));
typedef u16 u16x8 __attribute__((ext_vector_type(8)));

__device__ inline u16 f2bf(float x) {
  union { float f; unsigned u; } v; v.f = x;
  unsigned r = v.u + 0x7FFF + ((v.u >> 16) & 1);   // RNE
  return (u16)(r >> 16);
}

__device__ inline void glds16(const u16* g, const u16* l) {
  __builtin_amdgcn_global_load_lds(
      (const __attribute__((address_space(1))) void*)g,
      (__attribute__((address_space(3))) void*)l, 16, 0, 0);
}

// ---------------- fused memory-only prep ----------------
// blocks [0,4096):      cvt Q fp32 -> bf16
// blocks [4096,8192):   cvt K fp32 -> bf16
// blocks [8192,8768):   cvt rel fp32 -> bf16 padded [288][512]
// blocks [8768,12864):  transpose V [b][k][d] fp32 -> Vt [b][d][k] bf16
__global__ __launch_bounds__(256) void prep_mem_kernel(const float* __restrict__ Q,
                                                       const float* __restrict__ K,
                                                       const float* __restrict__ V,
                                                       const float* __restrict__ rel,
                                                       u16x4* __restrict__ Qb,
                                                       u16x4* __restrict__ Kb,
                                                       u16* __restrict__ relb,
                                                       u16* __restrict__ Vt) {
  __shared__ float tile[32][33];
  int bid = blockIdx.x, tid = threadIdx.x;
  if (bid < 8192) {
    const f32x4* src = (bid < 4096) ? (const f32x4*)Q : (const f32x4*)K;
    u16x4* dst = (bid < 4096) ? Qb : Kb;
    int i = (bid & 4095) * 256 + tid;     // exactly covers 1048576 f32x4
    f32x4 f = src[i];
    u16x4 o;
#pragma unroll
    for (int e = 0; e < 4; e++) o[e] = f2bf(f[e]);
    dst[i] = o;
  } else if (bid < 8768) {
    int i = (bid - 8192) * 256 + tid;     // < NRP*DIM
    int r = i >> 9;                       // / 512
    relb[i] = (r < NR) ? f2bf(rel[i]) : (u16)0;
  } else {
    int t = bid - 8768;
    int b = t >> 10, rem = t & 1023;
    int k0 = (rem & 63) * 32, d0 = (rem >> 6) * 32;
    int tx = tid & 31, ty = tid >> 5;     // 32 x 8
#pragma unroll
    for (int r = 0; r < 4; r++)
      tile[ty + r * 8][tx] = V[((long)b * SKL + k0 + ty + r * 8) * DIM + d0 + tx];
    __syncthreads();
#pragma unroll
    for (int r = 0; r < 4; r++)
      Vt[((long)b * DIM + d0 + ty + r * 8) * SKL + k0 + tx] = f2bf(tile[tx][ty + r * 8]);
  }
}

// ---------------- Qrel = Q @ rel^T : [8192][NRP] ----------------
// grid (128, 9) x 256 threads; wave w: rows m0+w*16..+16, col tiles {2y, 2y+1}
__global__ __launch_bounds__(256) void qrel_kernel(const u16* __restrict__ Qb,
                                                   const u16* __restrict__ relb,
                                                   float* __restrict__ Qrel) {
  int tid = threadIdx.x;
  int wave = tid >> 6, lane = tid & 63;
  int m0 = blockIdx.x * 64 + wave * 16;
  int j0 = blockIdx.y * 2;                 // col tiles j0, j0+1
  int fr = lane & 15, fk = (lane >> 4) * 8;
  f32x4 acc[2] = {};
  const u16* qrow = Qb + (long)(m0 + fr) * DIM + fk;
  const u16* r0 = relb + (long)(j0 * 16 + fr) * DIM + fk;
  const u16* r1 = r0 + 16 * DIM;
  for (int k0 = 0; k0 < DIM; k0 += 32) {
    bf16x8 a = *(const bf16x8*)(qrow + k0);
    bf16x8 b0 = *(const bf16x8*)(r0 + k0);
    bf16x8 b1 = *(const bf16x8*)(r1 + k0);
    acc[0] = __builtin_amdgcn_mfma_f32_16x16x32_bf16(a, b0, acc[0], 0, 0, 0);
    acc[1] = __builtin_amdgcn_mfma_f32_16x16x32_bf16(a, b1, acc[1], 0, 0, 0);
  }
  int cr = (lane >> 4) * 4, cc = lane & 15;
#pragma unroll
  for (int t = 0; t < 2; t++)
#pragma unroll
    for (int r = 0; r < 4; r++)
      Qrel[(long)(m0 + cr + r) * NRP + (j0 + t) * 16 + cc] = acc[t][r];
}

// ---------------- energy: S = bf16(Q K^T / sqrt(d)) (rel added in softmax) ----------------
// 128x128 tile, 4 waves (2x2 of 64x64), BK=32, global_load_lds staging
__global__ __launch_bounds__(256) void energy_kernel(const u16* __restrict__ Qb,
                                                     const u16* __restrict__ Kb,
                                                     u16* __restrict__ S) {
  int b = blockIdx.z;
  int m0 = blockIdx.y * 128;
  int n0 = blockIdx.x * 128;
  const u16* A = Qb + (long)b * SQL * DIM;
  const u16* Bp = Kb + (long)b * SKL * DIM;
  __shared__ u16 As[128 * 32];
  __shared__ u16 Bs[128 * 32];
  int tid = threadIdx.x;
  int wave = tid >> 6, lane = tid & 63;
  int wm = (wave >> 1) * 64, wn = (wave & 1) * 64;
  int fr = lane & 15, fk = (lane >> 4) * 8;
  int srow = wave * 32 + (lane >> 2);
  int scol = (lane & 3) * 8;
  f32x4 acc[4][4] = {};
  for (int k0 = 0; k0 < DIM; k0 += 32) {
    __syncthreads();
    glds16(A + (long)(m0 + srow) * DIM + k0 + scol, As + (wave * 2 + 0) * 512);
    glds16(A + (long)(m0 + srow + 16) * DIM + k0 + scol, As + (wave * 2 + 1) * 512);
    glds16(Bp + (long)(n0 + srow) * DIM + k0 + scol, Bs + (wave * 2 + 0) * 512);
    glds16(Bp + (long)(n0 + srow + 16) * DIM + k0 + scol, Bs + (wave * 2 + 1) * 512);
    __syncthreads();
    bf16x8 af[4], bfr[4];
#pragma unroll
    for (int i = 0; i < 4; i++) af[i] = *(const bf16x8*)(As + (wm + i * 16 + fr) * 32 + fk);
#pragma unroll
    for (int j = 0; j < 4; j++) bfr[j] = *(const bf16x8*)(Bs + (wn + j * 16 + fr) * 32 + fk);
#pragma unroll
    for (int i = 0; i < 4; i++)
#pragma unroll
      for (int j = 0; j < 4; j++)
        acc[i][j] = __builtin_amdgcn_mfma_f32_16x16x32_bf16(af[i], bfr[j], acc[i][j], 0, 0, 0);
  }
  const float inv_norm = 0.04419417382415922f;  // 1/sqrt(512)
  int cr = (lane >> 4) * 4, cc = lane & 15;
#pragma unroll
  for (int i = 0; i < 4; i++) {
#pragma unroll
    for (int r = 0; r < 4; r++) {
      int q = m0 + wm + i * 16 + cr + r;
      u16* sr = S + ((long)b * SQL + q) * SKL;
#pragma unroll
      for (int j = 0; j < 4; j++)
        sr[n0 + wn + j * 16 + cc] = f2bf(acc[i][j][r] * inv_norm);
    }
  }
}

// ---------------- softmax: logits + rel gather -> fp32 attn + bf16 probs (S in-place) ----
__global__ __launch_bounds__(256) void softmax_kernel(u16* __restrict__ S,
                                                      const float* __restrict__ Qrel,
                                                      float* __restrict__ attn) {
  long row = blockIdx.x;
  int q = (int)(row & (SQL - 1));
  u16* srow = S + row * SKL;
  float* arow = attn + row * SKL;
  int tid = threadIdx.x;
  int wave = tid >> 6, lane = tid & 63;
  __shared__ float qlds[NR];
  __shared__ float red[4];
  const float inv_norm = 0.04419417382415922f;
  const float* qr = Qrel + row * NRP;
  qlds[tid] = qr[tid] * inv_norm;          // tid 0..255
  if (tid == 0) qlds[256] = qr[256] * inv_norm;
  bf16x8 v = *(const bf16x8*)(srow + tid * 8);
  __syncthreads();
  float f[8];
  int kb = tid * 8 - q + RAD;
#pragma unroll
  for (int e = 0; e < 8; e++) {
    int idx = kb + e;
    idx = idx < 0 ? 0 : (idx > 2 * RAD ? 2 * RAD : idx);
    f[e] = (float)v[e] + qlds[idx];
  }
  float m = -1e30f;
#pragma unroll
  for (int e = 0; e < 8; e++) m = fmaxf(m, f[e]);
  for (int o = 32; o > 0; o >>= 1) m = fmaxf(m, __shfl_xor(m, o));
  if (lane == 0) red[wave] = m;
  __syncthreads();
  m = fmaxf(fmaxf(red[0], red[1]), fmaxf(red[2], red[3]));
  __syncthreads();
  float s = 0.0f;
  float e8[8];
#pragma unroll
  for (int e = 0; e < 8; e++) { e8[e] = __expf(f[e] - m); s += e8[e]; }
  for (int o = 32; o > 0; o >>= 1) s += __shfl_xor(s, o);
  if (lane == 0) red[wave] = s;
  __syncthreads();
  s = red[0] + red[1] + red[2] + red[3];
  float inv = 1.0f / s;
  f32x4 o0, o1;
  u16x8 pb;
#pragma unroll
  for (int e = 0; e < 4; e++) {
    float p = e8[e] * inv;
    o0[e] = p; pb[e] = f2bf(p);
  }
#pragma unroll
  for (int e = 0; e < 4; e++) {
    float p = e8[e + 4] * inv;
    o1[e] = p; pb[e + 4] = f2bf(p);
  }
  *(f32x4*)(arow + tid * 8) = o0;
  *(f32x4*)(arow + tid * 8 + 4) = o1;
  *(u16x8*)(srow + tid * 8) = pb;
}

// ---------------- Z = P @ V  (P = bf16 probs in S; Vt is [b][d][k] bf16) ----------------
// 64x128 tile (M x N), 4 waves (2x2 of 32x64), BK=32, global_load_lds staging
__global__ __launch_bounds__(256) void z_kernel(const u16* __restrict__ S,
                                                const u16* __restrict__ Vt,
                                                float* __restrict__ Z) {
  int b = blockIdx.z;
  int m0 = blockIdx.y * 64;
  int n0 = blockIdx.x * 128;
  const u16* A = S + (long)b * SQL * SKL;
  const u16* Bp = Vt + (long)b * DIM * SKL;
  __shared__ u16 As[64 * 32];
  __shared__ u16 Bs[128 * 32];
  int tid = threadIdx.x;
  int wave = tid >> 6, lane = tid & 63;
  int wm = (wave >> 1) * 32, wn = (wave & 1) * 64;
  int fr = lane & 15, fk = (lane >> 4) * 8;
  int srowA = wave * 16 + (lane >> 2);
  int srowB = wave * 32 + (lane >> 2);
  int scol = (lane & 3) * 8;
  f32x4 acc[2][4] = {};
  for (int k0 = 0; k0 < SKL; k0 += 32) {
    __syncthreads();
    glds16(A + (long)(m0 + srowA) * SKL + k0 + scol, As + wave * 512);
    glds16(Bp + (long)(n0 + srowB) * SKL + k0 + scol, Bs + (wave * 2 + 0) * 512);
    glds16(Bp + (long)(n0 + srowB + 16) * SKL + k0 + scol, Bs + (wave * 2 + 1) * 512);
    __syncthreads();
    bf16x8 af[2], bfr[4];
#pragma unroll
    for (int i = 0; i < 2; i++) af[i] = *(const bf16x8*)(As + (wm + i * 16 + fr) * 32 + fk);
#pragma unroll
    for (int j = 0; j < 4; j++) bfr[j] = *(const bf16x8*)(Bs + (wn + j * 16 + fr) * 32 + fk);
#pragma unroll
    for (int i = 0; i < 2; i++)
#pragma unroll
      for (int j = 0; j < 4; j++)
        acc[i][j] = __builtin_amdgcn_mfma_f32_16x16x32_bf16(af[i], bfr[j], acc[i][j], 0, 0, 0);
  }
  int cr = (lane >> 4) * 4, cc = lane & 15;
#pragma unroll
  for (int i = 0; i < 2; i++)
#pragma unroll
    for (int r = 0; r < 4; r++) {
      int q = m0 + wm + i * 16 + cr + r;
      float* zrow = Z + ((long)b * SQL + q) * DIM;
#pragma unroll
      for (int j = 0; j < 4; j++)
        zrow[n0 + wn + j * 16 + cc] = acc[i][j][r];
    }
}

// ---------------- launch ----------------

extern "C" void kernel_launch(void* const* d_in, const int* in_sizes, int n_in,
                              void* d_out, int out_size, void* d_ws, size_t ws_size,
                              hipStream_t stream) {
  const float* Q = (const float*)d_in[0];
  const float* K = (const float*)d_in[1];
  const float* V = (const float*)d_in[2];
  const float* rel = (const float*)d_in[3];
  float* attn = (float*)d_out;                       // [4][2048][2048]
  float* Z = attn + (long)BATCH * SQL * SKL;         // [4][2048][512]

  char* ws = (char*)d_ws;
  u16* Qb   = (u16*)ws;                    //  8 MiB  bf16 Q [b][q][d]
  u16* Kb   = (u16*)(ws + 8388608);        //  8 MiB  bf16 K [b][k][d]
  u16* Vt   = (u16*)(ws + 16777216);       //  8 MiB  bf16 V^T [b][d][k]
  u16* relb = (u16*)(ws + 25165824);       //  288 KiB bf16 rel padded [288][512]
  float* Qrel = (float*)(ws + 25460736);   //  9 MiB  fp32 Qrel [8192][288]
  u16* S    = (u16*)(ws + 34897920);       //  32 MiB bf16 scores/probs [b][q][k]

  prep_mem_kernel<<<12864, 256, 0, stream>>>(Q, K, V, rel, (u16x4*)Qb, (u16x4*)Kb, relb, Vt);
  qrel_kernel<<<dim3(128, 9), 256, 0, stream>>>(Qb, relb, Qrel);
  energy_kernel<<<dim3(16, 16, BATCH), 256, 0, stream>>>(Qb, Kb, S);
  softmax_kernel<<<8192, 256, 0, stream>>>(S, Qrel, attn);
  z_kernel<<<dim3(4, 32, BATCH), 256, 0, stream>>>(S, Vt, Z);
}

// Round 3
// 232.665 us; speedup vs baseline: 1.2062x; 1.0306x over previous
//
#include <hip/hip_runtime.h>

#define BATCH 4
#define SQL 2048
#define SKL 2048
#define DIM 512
#define NR 257
#define NRP 288
#define RAD 128

typedef __bf16 bf16x8 __attribute__((ext_vector_type(8)));
typedef float f32x4 __attribute__((ext_vector_type(4)));
typedef unsigned short u16;
typedef u16 u16x4 __attribute__((ext_vector_type(4)));
typedef u16 u16x8 __attribute__((ext_vector_type(8)));

__device__ inline u16 f2bf(float x) {
  union { float f; unsigned u; } v; v.f = x;
  unsigned r = v.u + 0x7FFF + ((v.u >> 16) & 1);   // RNE
  return (u16)(r >> 16);
}

__device__ inline void glds16(const u16* g, const u16* l) {
  __builtin_amdgcn_global_load_lds(
      (const __attribute__((address_space(1))) void*)g,
      (__attribute__((address_space(3))) void*)l, 16, 0, 0);
}

// ---------------- fused memory-only prep ----------------
// blocks [0,4096):      cvt Q fp32 -> bf16
// blocks [4096,8192):   cvt K fp32 -> bf16
// blocks [8192,8768):   cvt rel fp32 -> bf16 padded [288][512]
// blocks [8768,12864):  transpose V [b][k][d] fp32 -> Vt [b][d][k] bf16
__global__ __launch_bounds__(256) void prep_mem_kernel(const float* __restrict__ Q,
                                                       const float* __restrict__ K,
                                                       const float* __restrict__ V,
                                                       const float* __restrict__ rel,
                                                       u16x4* __restrict__ Qb,
                                                       u16x4* __restrict__ Kb,
                                                       u16* __restrict__ relb,
                                                       u16* __restrict__ Vt) {
  __shared__ float tile[32][33];
  int bid = blockIdx.x, tid = threadIdx.x;
  if (bid < 8192) {
    const f32x4* src = (bid < 4096) ? (const f32x4*)Q : (const f32x4*)K;
    u16x4* dst = (bid < 4096) ? Qb : Kb;
    int i = (bid & 4095) * 256 + tid;     // exactly covers 1048576 f32x4
    f32x4 f = src[i];
    u16x4 o;
#pragma unroll
    for (int e = 0; e < 4; e++) o[e] = f2bf(f[e]);
    dst[i] = o;
  } else if (bid < 8768) {
    int i = (bid - 8192) * 256 + tid;     // < NRP*DIM
    int r = i >> 9;                       // / 512
    relb[i] = (r < NR) ? f2bf(rel[i]) : (u16)0;
  } else {
    int t = bid - 8768;
    int b = t >> 10, rem = t & 1023;
    int k0 = (rem & 63) * 32, d0 = (rem >> 6) * 32;
    int tx = tid & 31, ty = tid >> 5;     // 32 x 8
#pragma unroll
    for (int r = 0; r < 4; r++)
      tile[ty + r * 8][tx] = V[((long)b * SKL + k0 + ty + r * 8) * DIM + d0 + tx];
    __syncthreads();
#pragma unroll
    for (int r = 0; r < 4; r++)
      Vt[((long)b * DIM + d0 + ty + r * 8) * SKL + k0 + tx] = f2bf(tile[tx][ty + r * 8]);
  }
}

// ---------------- Qrel = Q @ rel^T : [8192][NRP] ----------------
__global__ __launch_bounds__(256) void qrel_kernel(const u16* __restrict__ Qb,
                                                   const u16* __restrict__ relb,
                                                   float* __restrict__ Qrel) {
  int tid = threadIdx.x;
  int wave = tid >> 6, lane = tid & 63;
  int m0 = blockIdx.x * 64 + wave * 16;
  int j0 = blockIdx.y * 2;                 // col tiles j0, j0+1
  int fr = lane & 15, fk = (lane >> 4) * 8;
  f32x4 acc[2] = {};
  const u16* qrow = Qb + (long)(m0 + fr) * DIM + fk;
  const u16* r0 = relb + (long)(j0 * 16 + fr) * DIM + fk;
  const u16* r1 = r0 + 16 * DIM;
  for (int k0 = 0; k0 < DIM; k0 += 32) {
    bf16x8 a = *(const bf16x8*)(qrow + k0);
    bf16x8 b0 = *(const bf16x8*)(r0 + k0);
    bf16x8 b1 = *(const bf16x8*)(r1 + k0);
    acc[0] = __builtin_amdgcn_mfma_f32_16x16x32_bf16(a, b0, acc[0], 0, 0, 0);
    acc[1] = __builtin_amdgcn_mfma_f32_16x16x32_bf16(a, b1, acc[1], 0, 0, 0);
  }
  int cr = (lane >> 4) * 4, cc = lane & 15;
#pragma unroll
  for (int t = 0; t < 2; t++)
#pragma unroll
    for (int r = 0; r < 4; r++)
      Qrel[(long)(m0 + cr + r) * NRP + (j0 + t) * 16 + cc] = acc[t][r];
}

// ---------------- energy: S = bf16(Q K^T / sqrt(d)) ----------------
// 128x128 tile, 4 waves (2x2 of 64x64), BK=64, double-buffered LDS,
// 2-phase pipeline (stage next ∥ compute cur), T2 XOR-swizzled LDS.
// LDS layout: logical As[row][col] at byte row*128 + ((col*2) ^ ((row&7)<<4)).
// glds16 writes linearly -> source column is inverse-swizzled per lane.
__global__ __launch_bounds__(256) void energy_kernel(const u16* __restrict__ Qb,
                                                     const u16* __restrict__ Kb,
                                                     u16* __restrict__ S) {
  int b = blockIdx.z;
  int m0 = blockIdx.y * 128;
  int n0 = blockIdx.x * 128;
  const u16* A = Qb + (long)b * SQL * DIM;
  const u16* Bp = Kb + (long)b * SKL * DIM;
  __shared__ u16 lds[32768];               // 64 KiB: As0|Bs0|As1|Bs1 (8192 u16 each)
  u16* As0 = lds;          u16* Bs0 = lds + 8192;
  u16* As1 = lds + 16384;  u16* Bs1 = lds + 24576;
  int tid = threadIdx.x;
  int wave = tid >> 6, lane = tid & 63;
  int wm = (wave >> 1) * 64, wn = (wave & 1) * 64;
  int fr = lane & 15, g = lane >> 4;
  int srow = lane >> 3;                    // 0..7
  int scol = ((lane & 7) ^ srow) * 8;      // inverse-swizzled source col (elems)
  f32x4 acc[4][4] = {};

  auto stage = [&](u16* dA, u16* dB, int k0) {
#pragma unroll
    for (int c = 0; c < 4; c++) {
      int r = wave * 32 + c * 8;
      glds16(A + (long)(m0 + r + srow) * DIM + k0 + scol, dA + r * 64);
      glds16(Bp + (long)(n0 + r + srow) * DIM + k0 + scol, dB + r * 64);
    }
  };
  auto compute = [&](const u16* Asb, const u16* Bsb) {
#pragma unroll
    for (int s = 0; s < 2; s++) {
      bf16x8 af[4], bfv[4];
#pragma unroll
      for (int i = 0; i < 4; i++) {
        int row = wm + i * 16 + fr;
        int cb = (s * 64 + g * 16) ^ ((row & 7) << 4);
        af[i] = *(const bf16x8*)(Asb + row * 64 + (cb >> 1));
      }
#pragma unroll
      for (int j = 0; j < 4; j++) {
        int row = wn + j * 16 + fr;
        int cb = (s * 64 + g * 16) ^ ((row & 7) << 4);
        bfv[j] = *(const bf16x8*)(Bsb + row * 64 + (cb >> 1));
      }
#pragma unroll
      for (int i = 0; i < 4; i++)
#pragma unroll
        for (int j = 0; j < 4; j++)
          acc[i][j] = __builtin_amdgcn_mfma_f32_16x16x32_bf16(af[i], bfv[j], acc[i][j], 0, 0, 0);
    }
  };

  const int NT = DIM / 64;                 // 8
  stage(As0, Bs0, 0);
  __syncthreads();
  for (int t = 0; t < NT; t += 2) {
    if (t + 1 < NT) stage(As1, Bs1, (t + 1) * 64);
    compute(As0, Bs0);
    __syncthreads();
    if (t + 1 < NT) {
      if (t + 2 < NT) stage(As0, Bs0, (t + 2) * 64);
      compute(As1, Bs1);
      __syncthreads();
    }
  }

  const float inv_norm = 0.04419417382415922f;  // 1/sqrt(512)
  int cr = (lane >> 4) * 4, cc = lane & 15;
#pragma unroll
  for (int i = 0; i < 4; i++) {
#pragma unroll
    for (int r = 0; r < 4; r++) {
      int q = m0 + wm + i * 16 + cr + r;
      u16* sr = S + ((long)b * SQL + q) * SKL;
#pragma unroll
      for (int j = 0; j < 4; j++)
        sr[n0 + wn + j * 16 + cc] = f2bf(acc[i][j][r] * inv_norm);
    }
  }
}

// ---------------- softmax: logits + rel gather -> fp32 attn + bf16 probs (S in-place) ----
__global__ __launch_bounds__(256) void softmax_kernel(u16* __restrict__ S,
                                                      const float* __restrict__ Qrel,
                                                      float* __restrict__ attn) {
  long row = blockIdx.x;
  int q = (int)(row & (SQL - 1));
  u16* srow = S + row * SKL;
  float* arow = attn + row * SKL;
  int tid = threadIdx.x;
  int wave = tid >> 6, lane = tid & 63;
  __shared__ float qlds[NR];
  __shared__ float red[4];
  const float inv_norm = 0.04419417382415922f;
  const float* qr = Qrel + row * NRP;
  qlds[tid] = qr[tid] * inv_norm;          // tid 0..255
  if (tid == 0) qlds[256] = qr[256] * inv_norm;
  bf16x8 v = *(const bf16x8*)(srow + tid * 8);
  __syncthreads();
  float f[8];
  int kb = tid * 8 - q + RAD;
#pragma unroll
  for (int e = 0; e < 8; e++) {
    int idx = kb + e;
    idx = idx < 0 ? 0 : (idx > 2 * RAD ? 2 * RAD : idx);
    f[e] = (float)v[e] + qlds[idx];
  }
  float m = -1e30f;
#pragma unroll
  for (int e = 0; e < 8; e++) m = fmaxf(m, f[e]);
  for (int o = 32; o > 0; o >>= 1) m = fmaxf(m, __shfl_xor(m, o));
  if (lane == 0) red[wave] = m;
  __syncthreads();
  m = fmaxf(fmaxf(red[0], red[1]), fmaxf(red[2], red[3]));
  __syncthreads();
  float s = 0.0f;
  float e8[8];
#pragma unroll
  for (int e = 0; e < 8; e++) { e8[e] = __expf(f[e] - m); s += e8[e]; }
  for (int o = 32; o > 0; o >>= 1) s += __shfl_xor(s, o);
  if (lane == 0) red[wave] = s;
  __syncthreads();
  s = red[0] + red[1] + red[2] + red[3];
  float inv = 1.0f / s;
  f32x4 o0, o1;
  u16x8 pb;
#pragma unroll
  for (int e = 0; e < 4; e++) {
    float p = e8[e] * inv;
    o0[e] = p; pb[e] = f2bf(p);
  }
#pragma unroll
  for (int e = 0; e < 4; e++) {
    float p = e8[e + 4] * inv;
    o1[e] = p; pb[e + 4] = f2bf(p);
  }
  *(f32x4*)(arow + tid * 8) = o0;
  *(f32x4*)(arow + tid * 8 + 4) = o1;
  *(u16x8*)(srow + tid * 8) = pb;
}

// ---------------- Z = P @ V  (P = bf16 probs in S; Vt is [b][d][k] bf16) ----------------
// 64x128 tile (M x N), 4 waves (2x2 of 32x64), BK=64, double-buffered LDS,
// 2-phase pipeline + T2 XOR swizzle (same scheme as energy).
__global__ __launch_bounds__(256) void z_kernel(const u16* __restrict__ S,
                                                const u16* __restrict__ Vt,
                                                float* __restrict__ Z) {
  int b = blockIdx.z;
  int m0 = blockIdx.y * 64;
  int n0 = blockIdx.x * 128;
  const u16* A = S + (long)b * SQL * SKL;
  const u16* Bp = Vt + (long)b * DIM * SKL;
  __shared__ u16 lds[24576];               // 48 KiB: As0(4096)|Bs0(8192)|As1|Bs1
  u16* As0 = lds;          u16* Bs0 = lds + 4096;
  u16* As1 = lds + 12288;  u16* Bs1 = lds + 16384;
  int tid = threadIdx.x;
  int wave = tid >> 6, lane = tid & 63;
  int wm = (wave >> 1) * 32, wn = (wave & 1) * 64;
  int fr = lane & 15, g = lane >> 4;
  int srow = lane >> 3;
  int scol = ((lane & 7) ^ srow) * 8;
  f32x4 acc[2][4] = {};

  auto stage = [&](u16* dA, u16* dB, int k0) {
#pragma unroll
    for (int c = 0; c < 2; c++) {
      int r = wave * 16 + c * 8;
      glds16(A + (long)(m0 + r + srow) * SKL + k0 + scol, dA + r * 64);
    }
#pragma unroll
    for (int c = 0; c < 4; c++) {
      int r = wave * 32 + c * 8;
      glds16(Bp + (long)(n0 + r + srow) * SKL + k0 + scol, dB + r * 64);
    }
  };
  auto compute = [&](const u16* Asb, const u16* Bsb) {
#pragma unroll
    for (int s = 0; s < 2; s++) {
      bf16x8 af[2], bfv[4];
#pragma unroll
      for (int i = 0; i < 2; i++) {
        int row = wm + i * 16 + fr;
        int cb = (s * 64 + g * 16) ^ ((row & 7) << 4);
        af[i] = *(const bf16x8*)(Asb + row * 64 + (cb >> 1));
      }
#pragma unroll
      for (int j = 0; j < 4; j++) {
        int row = wn + j * 16 + fr;
        int cb = (s * 64 + g * 16) ^ ((row & 7) << 4);
        bfv[j] = *(const bf16x8*)(Bsb + row * 64 + (cb >> 1));
      }
#pragma unroll
      for (int i = 0; i < 2; i++)
#pragma unroll
        for (int j = 0; j < 4; j++)
          acc[i][j] = __builtin_amdgcn_mfma_f32_16x16x32_bf16(af[i], bfv[j], acc[i][j], 0, 0, 0);
    }
  };

  const int NT = SKL / 64;                 // 32
  stage(As0, Bs0, 0);
  __syncthreads();
  for (int t = 0; t < NT; t += 2) {
    if (t + 1 < NT) stage(As1, Bs1, (t + 1) * 64);
    compute(As0, Bs0);
    __syncthreads();
    if (t + 1 < NT) {
      if (t + 2 < NT) stage(As0, Bs0, (t + 2) * 64);
      compute(As1, Bs1);
      __syncthreads();
    }
  }

  int cr = (lane >> 4) * 4, cc = lane & 15;
#pragma unroll
  for (int i = 0; i < 2; i++)
#pragma unroll
    for (int r = 0; r < 4; r++) {
      int q = m0 + wm + i * 16 + cr + r;
      float* zrow = Z + ((long)b * SQL + q) * DIM;
#pragma unroll
      for (int j = 0; j < 4; j++)
        zrow[n0 + wn + j * 16 + cc] = acc[i][j][r];
    }
}

// ---------------- launch ----------------

extern "C" void kernel_launch(void* const* d_in, const int* in_sizes, int n_in,
                              void* d_out, int out_size, void* d_ws, size_t ws_size,
                              hipStream_t stream) {
  const float* Q = (const float*)d_in[0];
  const float* K = (const float*)d_in[1];
  const float* V = (const float*)d_in[2];
  const float* rel = (const float*)d_in[3];
  float* attn = (float*)d_out;                       // [4][2048][2048]
  float* Z = attn + (long)BATCH * SQL * SKL;         // [4][2048][512]

  char* ws = (char*)d_ws;
  u16* Qb   = (u16*)ws;                    //  8 MiB  bf16 Q [b][q][d]
  u16* Kb   = (u16*)(ws + 8388608);        //  8 MiB  bf16 K [b][k][d]
  u16* Vt   = (u16*)(ws + 16777216);       //  8 MiB  bf16 V^T [b][d][k]
  u16* relb = (u16*)(ws + 25165824);       //  288 KiB bf16 rel padded [288][512]
  float* Qrel = (float*)(ws + 25460736);   //  9 MiB  fp32 Qrel [8192][288]
  u16* S    = (u16*)(ws + 34897920);       //  32 MiB bf16 scores/probs [b][q][k]

  prep_mem_kernel<<<12864, 256, 0, stream>>>(Q, K, V, rel, (u16x4*)Qb, (u16x4*)Kb, relb, Vt);
  qrel_kernel<<<dim3(128, 9), 256, 0, stream>>>(Qb, relb, Qrel);
  energy_kernel<<<dim3(16, 16, BATCH), 256, 0, stream>>>(Qb, Kb, S);
  softmax_kernel<<<8192, 256, 0, stream>>>(S, Qrel, attn);
  z_kernel<<<dim3(4, 32, BATCH), 256, 0, stream>>>(S, Vt, Z);
}